// Round 8
// baseline (507.637 us; speedup 1.0000x reference)
//
#include <hip/hip_runtime.h>
#include <math.h>

// ---------------------------------------------------------------------------
// PCSQCNN: FRQI encode -> [QFT2D -> mux -> IQFT2D -> pool]^3 -> |.|^2 -> linear
//
// Global layout: S[b][X][f][Y] (float2), row base = ((b*128+X)*2+f)*128.
//
// Round 8: shuffle-FFT. Lane-cyclic ownership idx = j + 32q (lane j, reg q):
//   h=64,32 : register pairs within a lane (bfly on r[q])
//   h<=16   : lanes j <-> j^h via __shfl_xor(h)  (no LDS, no barriers)
//   f-pair  : lanes j <-> j^32 via __shfl_xor(32) (mux)
// Twiddles: 7 per-lane registers via sincosf (same values as the old table).
// k1/k3/k5: zero LDS, zero barriers. k2/k4: only the 2 staged-transpose
// barriers (global coalescing), Y0 XCD-share swizzle kept (verified round 6).
// Butterfly pairs / twiddles / op order identical to the verified chain.
// ---------------------------------------------------------------------------

#define PI_F 3.14159265358979323846f
#define PITCH 144            // staging line pitch (f2)
#define BUFSZ (8 * PITCH)

__device__ __forceinline__ float2 cmul(float2 a, float2 b) {
    return make_float2(a.x * b.x - a.y * b.y, a.x * b.y + a.y * b.x);
}
__device__ __forceinline__ float2 cadd(float2 a, float2 b) {
    return make_float2(a.x + b.x, a.y + b.y);
}
// DIF butterfly: u' = u+v ; v' = (u-v)*w
__device__ __forceinline__ void bfly_dif(float2& u, float2& v, float2 w) {
    float tx = u.x - v.x, ty = u.y - v.y;
    u.x += v.x; u.y += v.y;
    v.x = tx * w.x - ty * w.y;
    v.y = tx * w.y + ty * w.x;
}
// DIT inverse butterfly: t = v*conj(w); u' = u+t ; v' = u-t
__device__ __forceinline__ void bfly_dit(float2& u, float2& v, float2 w) {
    float tx = v.x * w.x + v.y * w.y, ty = v.y * w.x - v.x * w.y;
    v.x = u.x - tx; v.y = u.y - ty;
    u.x += tx; u.y += ty;
}

// per-lane twiddles: tw(k) = exp(-2*pi*i*k/128)
struct Tw { float2 w64a, w64b, w32, w16, w8, w4, w2; };
__device__ __forceinline__ float2 twv(int k) {
    float s, c;
    sincosf(-(2.0f * PI_F / 128.0f) * (float)k, &s, &c);
    return make_float2(c, s);
}
__device__ __forceinline__ Tw tw_make(int j) {
    Tw t;
    t.w64a = twv(j);
    t.w64b = twv(j + 32);
    t.w32  = twv(2 * j);
    t.w16  = twv(4 * (j & 15));
    t.w8   = twv(8 * (j & 7));
    t.w4   = twv(16 * (j & 3));
    t.w2   = twv(32 * (j & 1));
    return t;
}
// per-lane level constants
struct LC {
    float s1, s2, s4, s8, s16;
    bool h2, h4, h8, h16;
    float2 e2, e4, e8, e16;  // DIF post-mul: hi ? w : (1,0)
};
__device__ __forceinline__ LC lc_make(int j, const Tw& T) {
    LC c;
    const float2 ONE = make_float2(1.0f, 0.0f);
    c.h2 = (j & 2) != 0; c.h4 = (j & 4) != 0;
    c.h8 = (j & 8) != 0; c.h16 = (j & 16) != 0;
    c.s1 = (j & 1) ? -1.0f : 1.0f;
    c.s2 = c.h2 ? -1.0f : 1.0f;
    c.s4 = c.h4 ? -1.0f : 1.0f;
    c.s8 = c.h8 ? -1.0f : 1.0f;
    c.s16 = c.h16 ? -1.0f : 1.0f;
    c.e2 = c.h2 ? T.w2 : ONE;
    c.e4 = c.h4 ? T.w4 : ONE;
    c.e8 = c.h8 ? T.w8 : ONE;
    c.e16 = c.h16 ? T.w16 : ONE;
    return c;
}

// DIF shuffle level: pair (lane j, j^H); lo: r+p ; hi: (p-r)*w
template <int H>
__device__ __forceinline__ void lvl_dif(float2 r[4], float sgn, float2 we) {
#pragma unroll
    for (int q = 0; q < 4; ++q) {
        float px = __shfl_xor(r[q].x, H);
        float py = __shfl_xor(r[q].y, H);
        float tx = fmaf(sgn, r[q].x, px);
        float ty = fmaf(sgn, r[q].y, py);
        if constexpr (H == 1) {
            r[q] = make_float2(tx, ty);
        } else {
            r[q] = make_float2(tx * we.x - ty * we.y, tx * we.y + ty * we.x);
        }
    }
}
// DIT shuffle level: hi pre-multiplies own v by conj(w), then exchange;
// lo: u + v*cw ; hi: u - v*cw
template <int H>
__device__ __forceinline__ void lvl_dit(float2 r[4], float sgn, bool hi,
                                        float2 w) {
#pragma unroll
    for (int q = 0; q < 4; ++q) {
        float ax, ay;
        if constexpr (H == 1) {
            ax = r[q].x; ay = r[q].y;
        } else {
            float cx = r[q].x * w.x + r[q].y * w.y;   // r * conj(w)
            float cy = r[q].y * w.x - r[q].x * w.y;
            ax = hi ? cx : r[q].x;
            ay = hi ? cy : r[q].y;
        }
        float px = __shfl_xor(ax, H);
        float py = __shfl_xor(ay, H);
        r[q].x = fmaf(sgn, ax, px);
        r[q].y = fmaf(sgn, ay, py);
    }
}

// composite level sequences (universal twiddle: same formula per h in any
// aligned segment size)
__device__ __forceinline__ void dif_tail(float2 r[4], const LC& c) {
    lvl_dif<16>(r, c.s16, c.e16);
    lvl_dif<8>(r, c.s8, c.e8);
    lvl_dif<4>(r, c.s4, c.e4);
    lvl_dif<2>(r, c.s2, c.e2);
    lvl_dif<1>(r, c.s1, c.e2);
}
__device__ __forceinline__ void dit_head(float2 r[4], const Tw& T, const LC& c) {
    lvl_dit<1>(r, c.s1, false, T.w2);
    lvl_dit<2>(r, c.s2, c.h2, T.w2);
    lvl_dit<4>(r, c.s4, c.h4, T.w4);
    lvl_dit<8>(r, c.s8, c.h8, T.w8);
    lvl_dit<16>(r, c.s16, c.h16, T.w16);
}
__device__ __forceinline__ void dif128(float2 r[4], const Tw& T, const LC& c) {
    bfly_dif(r[0], r[2], T.w64a); bfly_dif(r[1], r[3], T.w64b);   // h=64
    bfly_dif(r[0], r[1], T.w32);  bfly_dif(r[2], r[3], T.w32);    // h=32
    dif_tail(r, c);
}
__device__ __forceinline__ void dit128(float2 r[4], const Tw& T, const LC& c) {
    dit_head(r, T, c);
    bfly_dit(r[0], r[1], T.w32);  bfly_dit(r[2], r[3], T.w32);    // h=32
    bfly_dit(r[0], r[2], T.w64a); bfly_dit(r[1], r[3], T.w64b);   // h=64
}
__device__ __forceinline__ void dif64(float2 r[4], const Tw& T, const LC& c) {
    bfly_dif(r[0], r[1], T.w32); bfly_dif(r[2], r[3], T.w32);     // h=32
    dif_tail(r, c);
}
__device__ __forceinline__ void dit64(float2 r[4], const Tw& T, const LC& c) {
    dit_head(r, T, c);
    bfly_dit(r[0], r[1], T.w32); bfly_dit(r[2], r[3], T.w32);     // h=32
}

// mux on one register: f-partner via shfl_xor(32); U = 4-entry base
__device__ __forceinline__ void mux_q(float2& rq, bool fb, const float2* U) {
    float2 pp;
    pp.x = __shfl_xor(rq.x, 32);
    pp.y = __shfl_xor(rq.y, 32);
    float2 x0 = fb ? pp : rq;
    float2 x1 = fb ? rq : pp;
    const float4 uv = *(const float4*)(U + (fb ? 2 : 0));
    rq = cadd(cmul(make_float2(uv.x, uv.y), x0),
              cmul(make_float2(uv.z, uv.w), x1));
}

// staging LDS address (k2/k4 transposes only)
__device__ __forceinline__ int pa(int L, int idx) {
    return L * PITCH + idx + (idx >> 3);
}

// ---------------------------------------------------------------------------
// K0: mux U tables, pre-permuted by bit-reversal (unchanged).
// ---------------------------------------------------------------------------
__global__ __launch_bounds__(256) void k0_prep(const float* __restrict__ mux0,
                                               const float* __restrict__ mux1,
                                               const float* __restrict__ mux2,
                                               float2* __restrict__ U0,
                                               float2* __restrict__ U1,
                                               float2* __restrict__ U2) {
    int t = blockIdx.x * 256 + threadIdx.x;
    const float* src;
    float2* dst;
    if (t < 16384) {
        int xb = t >> 7, yb = t & 127;
        int rx = __brev((unsigned)xb) >> 25;
        int ry = __brev((unsigned)yb) >> 25;
        src = mux0 + ((size_t)rx * 128 + ry) * 3;
        dst = U0 + (size_t)t * 4;
    } else if (t < 32768) {
        int u = t - 16384;
        int yam = u & 63, xam = (u >> 6) & 63, cy = (u >> 12) & 1, cx = (u >> 13) & 1;
        int rx = __brev((unsigned)xam) >> 26;
        int ry = __brev((unsigned)yam) >> 26;
        src = mux1 + ((size_t)(((cx * 2 + cy) * 64 + rx) * 64 + ry)) * 3;
        dst = U1 + (size_t)u * 4;
    } else if (t < 36864) {
        int u = t - 32768;
        int yam = u & 31, xam = (u >> 5) & 31, cy = (u >> 10) & 1, cx = (u >> 11) & 1;
        int rx = __brev((unsigned)xam) >> 27;
        int ry = __brev((unsigned)yam) >> 27;
        src = mux2 + ((size_t)(((cx * 2 + cy) * 32 + rx) * 32 + ry)) * 3;
        dst = U2 + (size_t)u * 4;
    } else {
        return;
    }
    float ax = src[0], ay = src[1], az = src[2];
    float r = sqrtf(ax * ax + ay * ay + az * az + 1e-20f);
    float cr = cosf(r);
    float snr = sinf(r) / r;
    dst[0] = make_float2(cr, -az * snr);
    dst[1] = make_float2(-ay * snr, -ax * snr);
    dst[2] = make_float2(ay * snr, -ax * snr);
    dst[3] = make_float2(cr, az * snr);
}

// ---------------------------------------------------------------------------
// K1: FRQI encode + FFT_Y128. Lines L = row*2+f. No LDS, no barriers.
// ---------------------------------------------------------------------------
__global__ __launch_bounds__(256) void k1_encode(const float* __restrict__ img,
                                                 float2* __restrict__ S) {
    int tid = threadIdx.x;
    int j = tid & 31, L = tid >> 5;
    int row = L >> 1, f = L & 1;
    int b = blockIdx.x >> 5;
    int X0 = (blockIdx.x & 31) * 4;
    Tw T = tw_make(j);
    LC c = lc_make(j, T);
    const float* ip = img + ((size_t)(b * 128) + X0 + row) * 128;
    float2 r[4];
#pragma unroll
    for (int q = 0; q < 4; ++q) {
        float v = ip[j + 32 * q];
        float s, cc;
        sincosf(0.5f * PI_F * v, &s, &cc);
        r[q] = make_float2((f ? s : cc) * (1.0f / 128.0f), 0.0f);
    }
    dif128(r, T, c);
    float2* gl = S + ((size_t)((b * 128 + X0 + row) * 2 + f)) * 128;
#pragma unroll
    for (int q = 0; q < 4; ++q) gl[j + 32 * q] = r[q];
}

// ---------------------------------------------------------------------------
// K2: column pass. FFT_X128 -> M0 -> IFFT_X128 -> FFT_X64. Lines L = yl*2+f.
// Staged transposes (2 barriers); Y0 XCD-share swizzle.
// ---------------------------------------------------------------------------
__global__ __launch_bounds__(256) void k2_col0(float2* __restrict__ S,
                                               const float2* __restrict__ U0) {
    __shared__ float2 A[BUFSZ];
    int tid = threadIdx.x;
    int b = blockIdx.x >> 5;
    int s_ = blockIdx.x & 31;
    int Y0 = (((s_ & 7) << 2) | (s_ >> 3)) * 4;  // XCD-share swizzle
    {   // staged load: thread = (X, fl), 4 consecutive Y
        int X = tid & 127, fl = tid >> 7;
        const float4* gp = (const float4*)(S + ((size_t)((b * 128 + X) * 2 + fl)) * 128 + Y0);
        float4 v0 = gp[0], v1 = gp[1];
        A[pa(fl * 4 + 0, X)] = make_float2(v0.x, v0.y);
        A[pa(fl * 4 + 1, X)] = make_float2(v0.z, v0.w);
        A[pa(fl * 4 + 2, X)] = make_float2(v1.x, v1.y);
        A[pa(fl * 4 + 3, X)] = make_float2(v1.z, v1.w);
    }
    int j = tid & 31, L = tid >> 5;
    int yl = L >> 1;
    bool fb = (L & 1) != 0;
    Tw T = tw_make(j);
    LC c = lc_make(j, T);
    __syncthreads();
    float2 r[4];
#pragma unroll
    for (int q = 0; q < 4; ++q) r[q] = A[pa((fb ? 4 : 0) + yl, j + 32 * q)];
    dif128(r, T, c);                         // FFT_X128
#pragma unroll
    for (int q = 0; q < 4; ++q) {            // M0: X = idx, Y = Y0+yl
        int X = j + 32 * q;
        mux_q(r[q], fb, U0 + ((size_t)X * 128 + (Y0 + yl)) * 4);
    }
    dit128(r, T, c);                         // IFFT_X128
    dif64(r, T, c);                          // FFT_X64
    const float sc = 1.0f / 128.0f;          // IFFT128 norm
#pragma unroll
    for (int q = 0; q < 4; ++q)
        A[pa((fb ? 4 : 0) + yl, j + 32 * q)] =
            make_float2(r[q].x * sc, r[q].y * sc);
    __syncthreads();
    {   // staged store
        int X = tid & 127, fl = tid >> 7;
        float2 e0 = A[pa(fl * 4 + 0, X)], e1 = A[pa(fl * 4 + 1, X)];
        float2 e2 = A[pa(fl * 4 + 2, X)], e3 = A[pa(fl * 4 + 3, X)];
        float4* gp = (float4*)(S + ((size_t)((b * 128 + X) * 2 + fl)) * 128 + Y0);
        gp[0] = make_float4(e0.x, e0.y, e1.x, e1.y);
        gp[1] = make_float4(e2.x, e2.y, e3.x, e3.y);
    }
}

// ---------------------------------------------------------------------------
// K3: row pass. IFFT_Y128 -> FFT_Y64 -> M1 -> IFFT_Y64 -> FFT_Y32.
// Lines L = row*2+f. No LDS, no barriers.
// ---------------------------------------------------------------------------
__global__ __launch_bounds__(256) void k3_row1(float2* __restrict__ S,
                                               const float2* __restrict__ U1) {
    int tid = threadIdx.x;
    int j = tid & 31, L = tid >> 5;
    int row = L >> 1;
    bool fb = (L & 1) != 0;
    int b = blockIdx.x >> 5;
    int X0 = (blockIdx.x & 31) * 4;
    Tw T = tw_make(j);
    LC c = lc_make(j, T);
    float2* gl = S + ((size_t)((b * 128 + X0 + row) * 2 + (fb ? 1 : 0))) * 128;
    float2 r[4];
#pragma unroll
    for (int q = 0; q < 4; ++q) r[q] = gl[j + 32 * q];
    dit128(r, T, c);                         // IFFT_Y128
    dif64(r, T, c);                          // FFT_Y64
    {   // M1: X = X0+row, Y = idx
        int X = X0 + row;
        int cx = X >> 6, xam = X & 63;
#pragma unroll
        for (int q = 0; q < 4; ++q) {
            int Y = j + 32 * q;
            int cy = Y >> 6, yam = Y & 63;
            const float2* U =
                U1 + ((size_t)((((cx << 1) | cy) << 6 | xam) << 6 | yam)) * 4;
            mux_q(r[q], fb, U);
        }
    }
    dit64(r, T, c);                          // IFFT_Y64
    dif_tail(r, c);                          // FFT_Y32 (h=16..1)
    const float sc = 1.0f / 8192.0f;         // IFFT128 * IFFT64 norms
#pragma unroll
    for (int q = 0; q < 4; ++q)
        gl[j + 32 * q] = make_float2(r[q].x * sc, r[q].y * sc);
}

// ---------------------------------------------------------------------------
// K4: column pass. IFFT_X64 -> FFT_X32 -> M2 -> IFFT_X32. Lines L = yl*2+f.
// Staged transposes (2 barriers); Y0 swizzle.
// ---------------------------------------------------------------------------
__global__ __launch_bounds__(256) void k4_col2(float2* __restrict__ S,
                                               const float2* __restrict__ U2) {
    __shared__ float2 A[BUFSZ];
    int tid = threadIdx.x;
    int b = blockIdx.x >> 5;
    int s_ = blockIdx.x & 31;
    int Y0 = (((s_ & 7) << 2) | (s_ >> 3)) * 4;  // XCD-share swizzle
    {
        int X = tid & 127, fl = tid >> 7;
        const float4* gp = (const float4*)(S + ((size_t)((b * 128 + X) * 2 + fl)) * 128 + Y0);
        float4 v0 = gp[0], v1 = gp[1];
        A[pa(fl * 4 + 0, X)] = make_float2(v0.x, v0.y);
        A[pa(fl * 4 + 1, X)] = make_float2(v0.z, v0.w);
        A[pa(fl * 4 + 2, X)] = make_float2(v1.x, v1.y);
        A[pa(fl * 4 + 3, X)] = make_float2(v1.z, v1.w);
    }
    int j = tid & 31, L = tid >> 5;
    int yl = L >> 1;
    bool fb = (L & 1) != 0;
    Tw T = tw_make(j);
    LC c = lc_make(j, T);
    __syncthreads();
    float2 r[4];
#pragma unroll
    for (int q = 0; q < 4; ++q) r[q] = A[pa((fb ? 4 : 0) + yl, j + 32 * q)];
    dit64(r, T, c);                          // IFFT_X64
    dif_tail(r, c);                          // FFT_X32
    {   // M2: X = idx, Ym = Y0+yl
        int Ym = Y0 + yl;
        int cy = (Ym >> 5) & 1, yam = Ym & 31;
#pragma unroll
        for (int q = 0; q < 4; ++q) {
            int X = j + 32 * q;
            int cx = (X >> 5) & 1, xam = X & 31;
            const float2* U =
                U2 + ((size_t)((((cx << 1) | cy) << 5 | xam) << 5 | yam)) * 4;
            mux_q(r[q], fb, U);
        }
    }
    dit_head(r, T, c);                       // IFFT_X32 (h=1..16)
    const float sc = 1.0f / 2048.0f;         // IFFT64 * IFFT32 norms
#pragma unroll
    for (int q = 0; q < 4; ++q)
        A[pa((fb ? 4 : 0) + yl, j + 32 * q)] =
            make_float2(r[q].x * sc, r[q].y * sc);
    __syncthreads();
    {
        int X = tid & 127, fl = tid >> 7;
        float2 e0 = A[pa(fl * 4 + 0, X)], e1 = A[pa(fl * 4 + 1, X)];
        float2 e2 = A[pa(fl * 4 + 2, X)], e3 = A[pa(fl * 4 + 3, X)];
        float4* gp = (float4*)(S + ((size_t)((b * 128 + X) * 2 + fl)) * 128 + Y0);
        gp[0] = make_float4(e0.x, e0.y, e1.x, e1.y);
        gp[1] = make_float4(e2.x, e2.y, e3.x, e3.y);
    }
}

// ---------------------------------------------------------------------------
// K5: IFFT_Y32 + |.|^2 marginal. Block = (b, xa); lines L = row*2+f,
// rows X = xa + 32*row. Lane j holds ya=j, q = yc. One barrier.
// ---------------------------------------------------------------------------
__global__ __launch_bounds__(256) void k5_prob(const float2* __restrict__ S,
                                               float* __restrict__ prob) {
    __shared__ float sd[256];
    int tid = threadIdx.x;
    int j = tid & 31, L = tid >> 5;
    int row = L >> 1, f = L & 1;
    int b = blockIdx.x >> 5;
    int xa = blockIdx.x & 31;
    Tw T = tw_make(j);
    LC c = lc_make(j, T);
    const float2* gl =
        S + ((size_t)((b * 128 + xa + 32 * row) * 2 + f)) * 128;
    float2 r[4];
#pragma unroll
    for (int q = 0; q < 4; ++q) r[q] = gl[j + 32 * q];
    dit_head(r, T, c);                       // IFFT_Y32 -> Y natural
    float acc = 0.0f;
#pragma unroll
    for (int q = 0; q < 4; ++q) acc += r[q].x * r[q].x + r[q].y * r[q].y;
    sd[L * 32 + j] = acc;                    // per-(row,f,ya) partial
    __syncthreads();
    if (tid < 64) {
        int ya = tid & 31, ff = tid >> 5;
        float s = sd[(0 * 2 + ff) * 32 + ya] + sd[(1 * 2 + ff) * 32 + ya] +
                  sd[(2 * 2 + ff) * 32 + ya] + sd[(3 * 2 + ff) * 32 + ya];
        // remaining norm: (1/32)^2 for IFFT_Y32 inside |.|^2
        prob[((size_t)(b * 32 + xa) * 32 + ya) * 2 + ff] = s * (1.0f / 1024.0f);
    }
}

// ---------------------------------------------------------------------------
// K6: linear head, wave-shuffle reduction.
// ---------------------------------------------------------------------------
__global__ __launch_bounds__(256) void k6_linear(const float* __restrict__ prob,
                                                 const float* __restrict__ W,
                                                 const float* __restrict__ bv,
                                                 float* __restrict__ out) {
    __shared__ float red[40];
    int b = blockIdx.x;
    int tid = threadIdx.x;
    float acc[10];
#pragma unroll
    for (int c = 0; c < 10; ++c) acc[c] = 0.0f;
    for (int j = tid; j < 2048; j += 256) {
        float p = prob[(size_t)b * 2048 + j];
#pragma unroll
        for (int c = 0; c < 10; ++c) acc[c] += p * W[c * 2048 + j];
    }
    int wv = tid >> 6, ln = tid & 63;
#pragma unroll
    for (int c = 0; c < 10; ++c) {
        float s = acc[c];
        for (int off = 32; off > 0; off >>= 1) s += __shfl_down(s, off);
        if (ln == 0) red[wv * 10 + c] = s;
    }
    __syncthreads();
    if (tid < 10)
        out[b * 10 + tid] =
            red[tid] + red[10 + tid] + red[20 + tid] + red[30 + tid] + bv[tid];
}

// ---------------------------------------------------------------------------
extern "C" void kernel_launch(void* const* d_in, const int* in_sizes, int n_in,
                              void* d_out, int out_size, void* d_ws,
                              size_t ws_size, hipStream_t stream) {
    const float* images = (const float*)d_in[0];
    const float* mux0 = (const float*)d_in[1];
    const float* mux1 = (const float*)d_in[2];
    const float* mux2 = (const float*)d_in[3];
    const float* W = (const float*)d_in[4];
    const float* bv = (const float*)d_in[5];
    float* out = (float*)d_out;

    float2* ws0 = (float2*)d_ws;
    const size_t STATE_F2 = (size_t)512 * 128 * 128 * 2;  // 16,777,216
    float2* S = ws0;
    float2* U0 = ws0 + STATE_F2;
    float2* U1 = U0 + 65536;
    float2* U2 = U1 + 65536;
    float* prob = (float*)(U2 + 16384);
    const size_t needed =
        (STATE_F2 + 65536 + 65536 + 16384) * sizeof(float2) +
        (size_t)512 * 2048 * sizeof(float);
    if (ws_size < needed) return;

    k0_prep<<<144, 256, 0, stream>>>(mux0, mux1, mux2, U0, U1, U2);
    k1_encode<<<16384, 256, 0, stream>>>(images, S);
    k2_col0<<<16384, 256, 0, stream>>>(S, U0);
    k3_row1<<<16384, 256, 0, stream>>>(S, U1);
    k4_col2<<<16384, 256, 0, stream>>>(S, U2);
    k5_prob<<<16384, 256, 0, stream>>>(S, prob);
    k6_linear<<<512, 256, 0, stream>>>(prob, W, bv, out);
}

// Round 9
// 397.728 us; speedup vs baseline: 1.2763x; 1.2763x over previous
//
#include <hip/hip_runtime.h>
#include <math.h>

// ---------------------------------------------------------------------------
// PCSQCNN: FRQI encode -> [QFT2D -> mux -> IQFT2D -> pool]^3 -> |.|^2 -> linear
//
// Global layout: S[b][X][f][Y] (float2), row base = ((b*128+X)*2+f)*128.
// Row passes: direct global<->register I/O. Column passes: staged via LDS.
// k2/k4 Y0 XCD-share swizzle (verified round 6: k2 FETCH 262->~130MB).
//
// Round 9: SoA LDS (separate x/y float planes) + XOR bank swizzle
//   perm(idx) = idx ^ (b5*13) ^ (b6*22)   (bits: b5 -> {0,2,3}, b6 -> {1,2,4})
// GF(2) rank analysis: restricted to every ownership pattern used here the
// bank map is full-rank -> every wave64 b32 LDS op lands <=2 lanes/bank
// (conflict-free, m136). Arithmetic/ownership/barriers byte-identical to the
// verified round-7 kernel; only LDS storage format changed.
// ---------------------------------------------------------------------------

#define PI_F 3.14159265358979323846f
#define P_ 128               // line pitch (floats); perm is a bijection 0..127

__device__ __forceinline__ float2 cmul(float2 a, float2 b) {
    return make_float2(a.x * b.x - a.y * b.y, a.x * b.y + a.y * b.x);
}
__device__ __forceinline__ float2 cadd(float2 a, float2 b) {
    return make_float2(a.x + b.x, a.y + b.y);
}
__device__ __forceinline__ float2 scl(float2 a, float s) {
    return make_float2(a.x * s, a.y * s);
}
// DIF butterfly: u' = u+v ; v' = (u-v)*w
__device__ __forceinline__ void bfly_dif(float2& u, float2& v, float2 w) {
    float tx = u.x - v.x, ty = u.y - v.y;
    u.x += v.x; u.y += v.y;
    v.x = tx * w.x - ty * w.y;
    v.y = tx * w.y + ty * w.x;
}
__device__ __forceinline__ void bfly_dif1(float2& u, float2& v) {
    float tx = u.x - v.x, ty = u.y - v.y;
    u.x += v.x; u.y += v.y;
    v.x = tx; v.y = ty;
}
// DIT inverse butterfly: t = v*conj(w); u' = u+t ; v' = u-t
__device__ __forceinline__ void bfly_dit(float2& u, float2& v, float2 w) {
    float tx = v.x * w.x + v.y * w.y, ty = v.y * w.x - v.x * w.y;
    v.x = u.x - tx; v.y = u.y - ty;
    u.x += tx; u.y += ty;
}
__device__ __forceinline__ void bfly_dit1(float2& u, float2& v) {
    float tx = v.x, ty = v.y;
    v.x = u.x - tx; v.y = u.y - ty;
    u.x += tx; u.y += ty;
}

constexpr int clog2(int v) { return v <= 1 ? 0 : 1 + clog2(v >> 1); }

// LDS address: line L, storage idx 0..127, XOR bank swizzle (bijective).
__device__ __forceinline__ int pf(int L, int idx) {
    int m = ((idx & 32) ? 13 : 0) ^ ((idx & 64) ? 22 : 0);
    return L * P_ + (idx ^ m);
}

// Ownership: segment size N (<=128), stride S. Thread j (0..31 per line) owns
// idx[q] = seg*N + 4S*(jj/S) + (jj%S) + S*q.  o = jj%S (twiddle low part).
template <int N, int S>
__device__ __forceinline__ void oidx(int j, int i[4], int& o) {
    constexpr int TPS = N / 4;
    constexpr int LT = clog2(TPS);
    int s = j >> LT;
    int jj = j & (TPS - 1);
    o = jj & (S - 1);
    int base = s * N + ((jj & ~(S - 1)) << 2) + o;
    i[0] = base; i[1] = base + S; i[2] = base + 2 * S; i[3] = base + 3 * S;
}

// Two DIF levels h=2S then h=S on r[0..3] (ownership stride S)
template <int S>
__device__ __forceinline__ void dif_pair(float2 r[4], int o, const float2* tw) {
    bfly_dif(r[0], r[2], tw[o * (32 / S)]);
    bfly_dif(r[1], r[3], tw[(o + S) * (32 / S)]);
    float2 wc = tw[o * (64 / S)];
    bfly_dif(r[0], r[1], wc);
    bfly_dif(r[2], r[3], wc);
}
// Two DIT levels h=S then h=2S
template <int S>
__device__ __forceinline__ void dit_pair(float2 r[4], int o, const float2* tw) {
    float2 wc = tw[o * (64 / S)];
    bfly_dit(r[0], r[1], wc);
    bfly_dit(r[2], r[3], wc);
    bfly_dit(r[0], r[2], tw[o * (32 / S)]);
    bfly_dit(r[1], r[3], tw[(o + S) * (32 / S)]);
}

// SoA store/load of one float2 at swizzled address a
__device__ __forceinline__ void stf(float* bx, float* by, int a, float2 v) {
    bx[a] = v.x; by[a] = v.y;
}
__device__ __forceinline__ float2 ldf(const float* bx, const float* by, int a) {
    return make_float2(bx[a], by[a]);
}

// Wave-synchronous round trip (exchange within a 32-thread line = half wave).
template <int NW, int SW, int NR, int SR>
__device__ __forceinline__ int xchg(float* bx, float* by, int L, int j,
                                    float2 r[4]) {
    int iw[4], ow;
    oidx<NW, SW>(j, iw, ow);
    stf(bx, by, pf(L, iw[0]), r[0]); stf(bx, by, pf(L, iw[1]), r[1]);
    stf(bx, by, pf(L, iw[2]), r[2]); stf(bx, by, pf(L, iw[3]), r[3]);
    __builtin_amdgcn_wave_barrier();
    int ir[4], orr;
    oidx<NR, SR>(j, ir, orr);
    r[0] = ldf(bx, by, pf(L, ir[0])); r[1] = ldf(bx, by, pf(L, ir[1]));
    r[2] = ldf(bx, by, pf(L, ir[2])); r[3] = ldf(bx, by, pf(L, ir[3]));
    __builtin_amdgcn_wave_barrier();
    return orr;
}

__device__ __forceinline__ void tw_init(float2* tw, int tid) {
    if (tid < 64) {
        float s, c;
        sincosf(-(2.0f * PI_F / 128.0f) * (float)tid, &s, &c);
        tw[tid] = make_float2(c, s);
    }
}

// ---------------------------------------------------------------------------
// K0: precompute multiplex U tables, pre-permuted by bit-reversal (unchanged).
// ---------------------------------------------------------------------------
__global__ __launch_bounds__(256) void k0_prep(const float* __restrict__ mux0,
                                               const float* __restrict__ mux1,
                                               const float* __restrict__ mux2,
                                               float2* __restrict__ U0,
                                               float2* __restrict__ U1,
                                               float2* __restrict__ U2) {
    int t = blockIdx.x * 256 + threadIdx.x;
    const float* src;
    float2* dst;
    if (t < 16384) {
        int xb = t >> 7, yb = t & 127;
        int rx = __brev((unsigned)xb) >> 25;
        int ry = __brev((unsigned)yb) >> 25;
        src = mux0 + ((size_t)rx * 128 + ry) * 3;
        dst = U0 + (size_t)t * 4;
    } else if (t < 32768) {
        int u = t - 16384;
        int yam = u & 63, xam = (u >> 6) & 63, cy = (u >> 12) & 1, cx = (u >> 13) & 1;
        int rx = __brev((unsigned)xam) >> 26;
        int ry = __brev((unsigned)yam) >> 26;
        src = mux1 + ((size_t)(((cx * 2 + cy) * 64 + rx) * 64 + ry)) * 3;
        dst = U1 + (size_t)u * 4;
    } else if (t < 36864) {
        int u = t - 32768;
        int yam = u & 31, xam = (u >> 5) & 31, cy = (u >> 10) & 1, cx = (u >> 11) & 1;
        int rx = __brev((unsigned)xam) >> 27;
        int ry = __brev((unsigned)yam) >> 27;
        src = mux2 + ((size_t)(((cx * 2 + cy) * 32 + rx) * 32 + ry)) * 3;
        dst = U2 + (size_t)u * 4;
    } else {
        return;
    }
    float ax = src[0], ay = src[1], az = src[2];
    float r = sqrtf(ax * ax + ay * ay + az * az + 1e-20f);
    float cr = cosf(r);
    float snr = sinf(r) / r;
    dst[0] = make_float2(cr, -az * snr);
    dst[1] = make_float2(-ay * snr, -ax * snr);
    dst[2] = make_float2(ay * snr, -ax * snr);
    dst[3] = make_float2(cr, az * snr);
}

// ---------------------------------------------------------------------------
// K1: FRQI encode + DIF_Y128. Lines L = row*2+f (4 X-rows x 2 f). Direct I/O.
// ---------------------------------------------------------------------------
__global__ __launch_bounds__(256) void k1_encode(const float* __restrict__ img,
                                                 float2* __restrict__ S) {
    __shared__ float Ax[8 * P_], Ay[8 * P_], Bx[8 * P_], By[8 * P_];
    __shared__ float2 tw[64];
    int tid = threadIdx.x;
    tw_init(tw, tid);
    int b = blockIdx.x >> 5;
    int X0 = (blockIdx.x & 31) * 4;
    int L = tid >> 5, j = tid & 31;
    int row = L >> 1, f = L & 1;
    const float* ip = img + ((size_t)(b * 128) + X0 + row) * 128;
    float2 r[4];
#pragma unroll
    for (int q = 0; q < 4; ++q) {
        float v = ip[j + 32 * q];
        float s, c;
        sincosf(0.5f * PI_F * v, &s, &c);
        float a = f ? s : c;
        r[q] = make_float2(a * (1.0f / 128.0f), 0.0f);  // S32 ownership, natural Y
    }
    __syncthreads();                        // tw visibility
    dif_pair<32>(r, j, tw);                 // h=64,32
    int o = xchg<128, 32, 128, 8>(Ax, Ay, L, j, r);
    dif_pair<8>(r, o, tw);                  // h=16,8
    o = xchg<128, 8, 128, 2>(Bx, By, L, j, r);
    dif_pair<2>(r, o, tw);                  // h=4,2
    o = xchg<128, 2, 128, 1>(Ax, Ay, L, j, r);
    bfly_dif1(r[0], r[1]); bfly_dif1(r[2], r[3]);  // h=1
    float2* op = S + ((size_t)((b * 128 + X0 + row) * 2 + f)) * 128 + 4 * j;
    float4* gp = (float4*)op;
    gp[0] = make_float4(r[0].x, r[0].y, r[1].x, r[1].y);
    gp[1] = make_float4(r[2].x, r[2].y, r[3].x, r[3].y);
}

// ---------------------------------------------------------------------------
// K2: column pass. FFT_X128 -> M0 -> IFFT_X128 -> FFT_X64. Lines L = f*4+yl.
// Y0 swizzled so same-XCD blocks share cache lines.
// ---------------------------------------------------------------------------
__global__ __launch_bounds__(256) void k2_col0(float2* __restrict__ S,
                                               const float2* __restrict__ U0) {
    __shared__ float Ax[8 * P_], Ay[8 * P_], Bx[8 * P_], By[8 * P_];
    __shared__ float2 tw[64];
    int tid = threadIdx.x;
    tw_init(tw, tid);
    int b = blockIdx.x >> 5;
    int s_ = blockIdx.x & 31;
    int Y0 = (((s_ & 7) << 2) | (s_ >> 3)) * 4;  // XCD-share swizzle
    {   // staged load: thread = (X, f), 4 consecutive Y (2x float4)
        int X = tid & 127, f = tid >> 7;
        const float4* gp = (const float4*)(S + ((size_t)((b * 128 + X) * 2 + f)) * 128 + Y0);
        float4 v0 = gp[0], v1 = gp[1];
        stf(Ax, Ay, pf(f * 4 + 0, X), make_float2(v0.x, v0.y));
        stf(Ax, Ay, pf(f * 4 + 1, X), make_float2(v0.z, v0.w));
        stf(Ax, Ay, pf(f * 4 + 2, X), make_float2(v1.x, v1.y));
        stf(Ax, Ay, pf(f * 4 + 3, X), make_float2(v1.z, v1.w));
    }
    __syncthreads();                              // staging is cross-wave
    int L = tid >> 5, j = tid & 31;
    float2 r[4];
    int o;
    {
        int ir[4];
        oidx<128, 32>(j, ir, o);
        r[0] = ldf(Ax, Ay, pf(L, ir[0])); r[1] = ldf(Ax, Ay, pf(L, ir[1]));
        r[2] = ldf(Ax, Ay, pf(L, ir[2])); r[3] = ldf(Ax, Ay, pf(L, ir[3]));
    }
    dif_pair<32>(r, o, tw);                       // FFT128 h=64,32
    o = xchg<128, 32, 128, 8>(Bx, By, L, j, r);
    dif_pair<8>(r, o, tw);                        // h=16,8
    o = xchg<128, 8, 128, 2>(Ax, Ay, L, j, r);
    dif_pair<2>(r, o, tw);                        // h=4,2
    {   // -> f-pair ownership (cross-wave section: real barriers)
        int iw[4], ow;
        oidx<128, 2>(j, iw, ow);
        stf(Bx, By, pf(L, iw[0]), r[0]); stf(Bx, By, pf(L, iw[1]), r[1]);
        stf(Bx, By, pf(L, iw[2]), r[2]); stf(Bx, By, pf(L, iw[3]), r[3]);
    }
    __syncthreads();
    int yl = tid >> 6, m2 = (tid & 63) * 2;
    r[0] = ldf(Bx, By, pf(yl, m2));     r[1] = ldf(Bx, By, pf(4 + yl, m2));
    r[2] = ldf(Bx, By, pf(yl, m2 + 1)); r[3] = ldf(Bx, By, pf(4 + yl, m2 + 1));
    bfly_dif1(r[0], r[2]); bfly_dif1(r[1], r[3]);  // FFT128 h=1 (per f)
    {   // M0 (table pre-permuted rev7 x rev7)
        const float2* U = U0 + ((size_t)m2 * 128 + (Y0 + yl)) * 4;
        float2 p0 = r[0], p1 = r[1];
        r[0] = cadd(cmul(U[0], p0), cmul(U[1], p1));
        r[1] = cadd(cmul(U[2], p0), cmul(U[3], p1));
        U = U0 + ((size_t)(m2 + 1) * 128 + (Y0 + yl)) * 4;
        p0 = r[2]; p1 = r[3];
        r[2] = cadd(cmul(U[0], p0), cmul(U[1], p1));
        r[3] = cadd(cmul(U[2], p0), cmul(U[3], p1));
    }
    bfly_dit1(r[0], r[2]); bfly_dit1(r[1], r[3]);  // IFFT128 h=1
    stf(Ax, Ay, pf(yl, m2), r[0]);     stf(Ax, Ay, pf(4 + yl, m2), r[1]);
    stf(Ax, Ay, pf(yl, m2 + 1), r[2]); stf(Ax, Ay, pf(4 + yl, m2 + 1), r[3]);
    __syncthreads();
    {
        int ir[4];
        oidx<128, 2>(j, ir, o);
        r[0] = ldf(Ax, Ay, pf(L, ir[0])); r[1] = ldf(Ax, Ay, pf(L, ir[1]));
        r[2] = ldf(Ax, Ay, pf(L, ir[2])); r[3] = ldf(Ax, Ay, pf(L, ir[3]));
    }
    dit_pair<2>(r, o, tw);                        // h=2,4
    o = xchg<128, 2, 128, 8>(Bx, By, L, j, r);
    dit_pair<8>(r, o, tw);                        // h=8,16
    o = xchg<128, 8, 128, 32>(Ax, Ay, L, j, r);
    dit_pair<32>(r, o, tw);                       // h=32,64 -> X natural
    {   // fused FFT64 h=32 (segments (r0,r1),(r2,r3))
        float2 w = tw[2 * o];
        bfly_dif(r[0], r[1], w); bfly_dif(r[2], r[3], w);
    }
    o = xchg<128, 32, 64, 8>(Bx, By, L, j, r);
    dif_pair<8>(r, o, tw);                        // FFT64 h=16,8
    o = xchg<64, 8, 64, 2>(Ax, Ay, L, j, r);
    dif_pair<2>(r, o, tw);                        // h=4,2
    o = xchg<64, 2, 64, 1>(Bx, By, L, j, r);
    bfly_dif1(r[0], r[1]); bfly_dif1(r[2], r[3]); // h=1
    {
        int iw[4], ow;
        oidx<64, 1>(j, iw, ow);
        const float sc = 1.0f / 128.0f;           // IFFT128 norm
        stf(Ax, Ay, pf(L, iw[0]), scl(r[0], sc));
        stf(Ax, Ay, pf(L, iw[1]), scl(r[1], sc));
        stf(Ax, Ay, pf(L, iw[2]), scl(r[2], sc));
        stf(Ax, Ay, pf(L, iw[3]), scl(r[3], sc));
    }
    __syncthreads();                              // staged store is cross-wave
    {   // staged store
        int X = tid & 127, f = tid >> 7;
        float2 e0 = ldf(Ax, Ay, pf(f * 4 + 0, X));
        float2 e1 = ldf(Ax, Ay, pf(f * 4 + 1, X));
        float2 e2 = ldf(Ax, Ay, pf(f * 4 + 2, X));
        float2 e3 = ldf(Ax, Ay, pf(f * 4 + 3, X));
        float4* gp = (float4*)(S + ((size_t)((b * 128 + X) * 2 + f)) * 128 + Y0);
        gp[0] = make_float4(e0.x, e0.y, e1.x, e1.y);
        gp[1] = make_float4(e2.x, e2.y, e3.x, e3.y);
    }
}

// ---------------------------------------------------------------------------
// K3: row pass. IFFT_Y128 -> FFT_Y64 -> M1 -> IFFT_Y64 -> FFT_Y32.
// Lines L = row*2+f. Direct global I/O.
// ---------------------------------------------------------------------------
__global__ __launch_bounds__(256) void k3_row1(float2* __restrict__ S,
                                               const float2* __restrict__ U1) {
    __shared__ float Ax[8 * P_], Ay[8 * P_], Bx[8 * P_], By[8 * P_];
    __shared__ float2 tw[64];
    int tid = threadIdx.x;
    tw_init(tw, tid);
    int b = blockIdx.x >> 5;
    int X0 = (blockIdx.x & 31) * 4;
    int L = tid >> 5, j = tid & 31;
    int row = L >> 1, f = L & 1;
    float2* gl = S + ((size_t)((b * 128 + X0 + row) * 2 + f)) * 128;
    float2 r[4];
    {
        const float4* gp = (const float4*)(gl + 4 * j);
        float4 v0 = gp[0], v1 = gp[1];
        r[0] = make_float2(v0.x, v0.y); r[1] = make_float2(v0.z, v0.w);
        r[2] = make_float2(v1.x, v1.y); r[3] = make_float2(v1.z, v1.w);
    }
    __syncthreads();                              // tw visibility
    dit_pair<1>(r, 0, tw);                        // IFFT128 h=1,2
    int o = xchg<128, 1, 128, 4>(Ax, Ay, L, j, r);
    dit_pair<4>(r, o, tw);                        // h=4,8
    o = xchg<128, 4, 128, 16>(Bx, By, L, j, r);
    dit_pair<16>(r, o, tw);                       // h=16,32
    o = xchg<128, 16, 128, 32>(Ax, Ay, L, j, r);
    bfly_dit(r[0], r[2], tw[o]);                  // h=64 -> Y natural
    bfly_dit(r[1], r[3], tw[o + 32]);
    {   // fused FFT64 h=32
        float2 w = tw[2 * o];
        bfly_dif(r[0], r[1], w); bfly_dif(r[2], r[3], w);
    }
    o = xchg<128, 32, 64, 8>(Bx, By, L, j, r);
    dif_pair<8>(r, o, tw);                        // FFT64 h=16,8
    o = xchg<64, 8, 64, 2>(Ax, Ay, L, j, r);
    dif_pair<2>(r, o, tw);                        // h=4,2
    {   // -> f-pair ownership (cross-wave section: real barriers)
        int iw[4], ow;
        oidx<64, 2>(j, iw, ow);
        stf(Bx, By, pf(L, iw[0]), r[0]); stf(Bx, By, pf(L, iw[1]), r[1]);
        stf(Bx, By, pf(L, iw[2]), r[2]); stf(Bx, By, pf(L, iw[3]), r[3]);
    }
    __syncthreads();
    int row2 = tid >> 6, m2 = (tid & 63) * 2;
    r[0] = ldf(Bx, By, pf(row2 * 2, m2));
    r[1] = ldf(Bx, By, pf(row2 * 2 + 1, m2));
    r[2] = ldf(Bx, By, pf(row2 * 2, m2 + 1));
    r[3] = ldf(Bx, By, pf(row2 * 2 + 1, m2 + 1));
    bfly_dif1(r[0], r[2]); bfly_dif1(r[1], r[3]);  // FFT64 h=1 (per f)
    {   // M1: cx = X>>6, xam = X&63 (rev6 in table); same for Y
        int X = X0 + row2;
        int cx = X >> 6, xam = X & 63;
        int cy0 = m2 >> 6, yam0 = m2 & 63;
        const float2* U =
            U1 + ((size_t)((((cx << 1) | cy0) << 6 | xam) << 6 | yam0)) * 4;
        float2 p0 = r[0], p1 = r[1];
        r[0] = cadd(cmul(U[0], p0), cmul(U[1], p1));
        r[1] = cadd(cmul(U[2], p0), cmul(U[3], p1));
        int cy1 = (m2 + 1) >> 6, yam1 = (m2 + 1) & 63;
        U = U1 + ((size_t)((((cx << 1) | cy1) << 6 | xam) << 6 | yam1)) * 4;
        p0 = r[2]; p1 = r[3];
        r[2] = cadd(cmul(U[0], p0), cmul(U[1], p1));
        r[3] = cadd(cmul(U[2], p0), cmul(U[3], p1));
    }
    bfly_dit1(r[0], r[2]); bfly_dit1(r[1], r[3]);  // IFFT64 h=1
    stf(Ax, Ay, pf(row2 * 2, m2), r[0]);
    stf(Ax, Ay, pf(row2 * 2 + 1, m2), r[1]);
    stf(Ax, Ay, pf(row2 * 2, m2 + 1), r[2]);
    stf(Ax, Ay, pf(row2 * 2 + 1, m2 + 1), r[3]);
    __syncthreads();
    {
        int ir[4];
        oidx<64, 2>(j, ir, o);
        r[0] = ldf(Ax, Ay, pf(L, ir[0])); r[1] = ldf(Ax, Ay, pf(L, ir[1]));
        r[2] = ldf(Ax, Ay, pf(L, ir[2])); r[3] = ldf(Ax, Ay, pf(L, ir[3]));
    }
    dit_pair<2>(r, o, tw);                        // IFFT64 h=2,4
    o = xchg<64, 2, 64, 8>(Bx, By, L, j, r);
    dit_pair<8>(r, o, tw);                        // h=8,16
    o = xchg<64, 8, 64, 16>(Ax, Ay, L, j, r);
    bfly_dit(r[0], r[2], tw[2 * o]);              // IFFT64 h=32 -> natural
    bfly_dit(r[1], r[3], tw[2 * o + 32]);
    {   // fused FFT32 h=16
        float2 w = tw[4 * o];
        bfly_dif(r[0], r[1], w); bfly_dif(r[2], r[3], w);
    }
    o = xchg<64, 16, 32, 4>(Bx, By, L, j, r);
    dif_pair<4>(r, o, tw);                        // FFT32 h=8,4
    o = xchg<32, 4, 32, 1>(Ax, Ay, L, j, r);
    dif_pair<1>(r, 0, tw);                        // h=2,1
    {
        int iw[4], ow;
        oidx<32, 1>(j, iw, ow);
        const float sc = 1.0f / 8192.0f;          // IFFT128 * IFFT64 norms
        float4* gp = (float4*)(gl + iw[0]);
        gp[0] = make_float4(r[0].x * sc, r[0].y * sc, r[1].x * sc, r[1].y * sc);
        gp[1] = make_float4(r[2].x * sc, r[2].y * sc, r[3].x * sc, r[3].y * sc);
    }
}

// ---------------------------------------------------------------------------
// K4: column pass. IFFT_X64 -> FFT_X32 -> M2 -> IFFT_X32. Lines L = f*4+yl.
// Y0 swizzled (same scheme as K2).
// ---------------------------------------------------------------------------
__global__ __launch_bounds__(256) void k4_col2(float2* __restrict__ S,
                                               const float2* __restrict__ U2) {
    __shared__ float Ax[8 * P_], Ay[8 * P_], Bx[8 * P_], By[8 * P_];
    __shared__ float2 tw[64];
    int tid = threadIdx.x;
    tw_init(tw, tid);
    int b = blockIdx.x >> 5;
    int s_ = blockIdx.x & 31;
    int Y0 = (((s_ & 7) << 2) | (s_ >> 3)) * 4;  // XCD-share swizzle
    {
        int X = tid & 127, f = tid >> 7;
        const float4* gp = (const float4*)(S + ((size_t)((b * 128 + X) * 2 + f)) * 128 + Y0);
        float4 v0 = gp[0], v1 = gp[1];
        stf(Ax, Ay, pf(f * 4 + 0, X), make_float2(v0.x, v0.y));
        stf(Ax, Ay, pf(f * 4 + 1, X), make_float2(v0.z, v0.w));
        stf(Ax, Ay, pf(f * 4 + 2, X), make_float2(v1.x, v1.y));
        stf(Ax, Ay, pf(f * 4 + 3, X), make_float2(v1.z, v1.w));
    }
    __syncthreads();                              // staging is cross-wave
    int L = tid >> 5, j = tid & 31;
    float2 r[4];
    int o;
    {
        int ir[4];
        oidx<64, 1>(j, ir, o);
        r[0] = ldf(Ax, Ay, pf(L, ir[0])); r[1] = ldf(Ax, Ay, pf(L, ir[1]));
        r[2] = ldf(Ax, Ay, pf(L, ir[2])); r[3] = ldf(Ax, Ay, pf(L, ir[3]));
    }
    dit_pair<1>(r, 0, tw);                        // IFFT64 h=1,2
    o = xchg<64, 1, 64, 4>(Bx, By, L, j, r);
    dit_pair<4>(r, o, tw);                        // h=4,8
    o = xchg<64, 4, 64, 16>(Ax, Ay, L, j, r);
    dit_pair<16>(r, o, tw);                       // h=16,32 -> natural in 64
    {   // fused FFT32 h=16
        float2 w = tw[4 * o];
        bfly_dif(r[0], r[1], w); bfly_dif(r[2], r[3], w);
    }
    o = xchg<64, 16, 32, 4>(Bx, By, L, j, r);
    dif_pair<4>(r, o, tw);                        // FFT32 h=8,4
    o = xchg<32, 4, 32, 1>(Ax, Ay, L, j, r);
    dif_pair<1>(r, 0, tw);                        // h=2,1
    {   // -> f-pair ownership (cross-wave section: real barriers)
        int iw[4], ow;
        oidx<32, 1>(j, iw, ow);
        stf(Bx, By, pf(L, iw[0]), r[0]); stf(Bx, By, pf(L, iw[1]), r[1]);
        stf(Bx, By, pf(L, iw[2]), r[2]); stf(Bx, By, pf(L, iw[3]), r[3]);
    }
    __syncthreads();
    int yl = tid >> 6, m2 = (tid & 63) * 2;
    r[0] = ldf(Bx, By, pf(yl, m2));     r[1] = ldf(Bx, By, pf(4 + yl, m2));
    r[2] = ldf(Bx, By, pf(yl, m2 + 1)); r[3] = ldf(Bx, By, pf(4 + yl, m2 + 1));
    {   // M2: cx = (X>>5)&1, xam = X&31 (rev5 in table); Ym = Y0+yl
        int Ym = Y0 + yl;
        int cy = (Ym >> 5) & 1, yam = Ym & 31;
        int cx = (m2 >> 5) & 1, xam = m2 & 31;
        const float2* U =
            U2 + ((size_t)((((cx << 1) | cy) << 5 | xam) << 5 | yam)) * 4;
        float2 p0 = r[0], p1 = r[1];
        r[0] = cadd(cmul(U[0], p0), cmul(U[1], p1));
        r[1] = cadd(cmul(U[2], p0), cmul(U[3], p1));
        int X1 = m2 + 1;
        cx = (X1 >> 5) & 1; xam = X1 & 31;
        U = U2 + ((size_t)((((cx << 1) | cy) << 5 | xam) << 5 | yam)) * 4;
        p0 = r[2]; p1 = r[3];
        r[2] = cadd(cmul(U[0], p0), cmul(U[1], p1));
        r[3] = cadd(cmul(U[2], p0), cmul(U[3], p1));
    }
    bfly_dit1(r[0], r[2]); bfly_dit1(r[1], r[3]);  // IFFT32 h=1
    stf(Ax, Ay, pf(yl, m2), r[0]);     stf(Ax, Ay, pf(4 + yl, m2), r[1]);
    stf(Ax, Ay, pf(yl, m2 + 1), r[2]); stf(Ax, Ay, pf(4 + yl, m2 + 1), r[3]);
    __syncthreads();
    {
        int ir[4];
        oidx<32, 2>(j, ir, o);
        r[0] = ldf(Ax, Ay, pf(L, ir[0])); r[1] = ldf(Ax, Ay, pf(L, ir[1]));
        r[2] = ldf(Ax, Ay, pf(L, ir[2])); r[3] = ldf(Ax, Ay, pf(L, ir[3]));
    }
    dit_pair<2>(r, o, tw);                        // IFFT32 h=2,4
    o = xchg<32, 2, 32, 8>(Bx, By, L, j, r);
    dit_pair<8>(r, o, tw);                        // h=8,16 -> X natural
    {
        int iw[4], ow;
        oidx<32, 8>(j, iw, ow);
        const float sc = 1.0f / 2048.0f;          // IFFT64 * IFFT32 norms
        stf(Ax, Ay, pf(L, iw[0]), scl(r[0], sc));
        stf(Ax, Ay, pf(L, iw[1]), scl(r[1], sc));
        stf(Ax, Ay, pf(L, iw[2]), scl(r[2], sc));
        stf(Ax, Ay, pf(L, iw[3]), scl(r[3], sc));
    }
    __syncthreads();                              // staged store is cross-wave
    {
        int X = tid & 127, f = tid >> 7;
        float2 e0 = ldf(Ax, Ay, pf(f * 4 + 0, X));
        float2 e1 = ldf(Ax, Ay, pf(f * 4 + 1, X));
        float2 e2 = ldf(Ax, Ay, pf(f * 4 + 2, X));
        float2 e3 = ldf(Ax, Ay, pf(f * 4 + 3, X));
        float4* gp = (float4*)(S + ((size_t)((b * 128 + X) * 2 + f)) * 128 + Y0);
        gp[0] = make_float4(e0.x, e0.y, e1.x, e1.y);
        gp[1] = make_float4(e2.x, e2.y, e3.x, e3.y);
    }
}

// ---------------------------------------------------------------------------
// K5: row pass. IFFT_Y32 + |.|^2 summed over xc (4 rows) and yc (4 segs).
// Block = (b, xa): rows X = xa + {0,32,64,96}. Lines L = row*2+f.
// ---------------------------------------------------------------------------
__global__ __launch_bounds__(256) void k5_prob(const float2* __restrict__ S,
                                               float* __restrict__ prob) {
    __shared__ float Ax[8 * P_], Ay[8 * P_], Bx[8 * P_], By[8 * P_];
    __shared__ float2 tw[64];
    int tid = threadIdx.x;
    tw_init(tw, tid);
    int b = blockIdx.x >> 5;
    int xa = blockIdx.x & 31;
    int L = tid >> 5, j = tid & 31;
    int row = L >> 1, f = L & 1;
    const float2* gl = S + ((size_t)((b * 128 + xa + 32 * row) * 2 + f)) * 128;
    float2 r[4];
    int o;
    int i0[4];
    oidx<32, 1>(j, i0, o);
    {
        const float4* gp = (const float4*)(gl + i0[0]);
        float4 v0 = gp[0], v1 = gp[1];
        r[0] = make_float2(v0.x, v0.y); r[1] = make_float2(v0.z, v0.w);
        r[2] = make_float2(v1.x, v1.y); r[3] = make_float2(v1.z, v1.w);
    }
    __syncthreads();                              // tw visibility
    dit_pair<1>(r, 0, tw);                        // IFFT32 h=1,2
    o = xchg<32, 1, 32, 4>(Ax, Ay, L, j, r);
    dit_pair<4>(r, o, tw);                        // h=4,8
    o = xchg<32, 4, 32, 8>(Bx, By, L, j, r);
    bfly_dit(r[0], r[2], tw[4 * o]);              // h=16 -> Y natural
    bfly_dit(r[1], r[3], tw[4 * o + 32]);
    {
        int iw[4], ow;
        oidx<32, 8>(j, iw, ow);
        stf(Ax, Ay, pf(L, iw[0]), r[0]); stf(Ax, Ay, pf(L, iw[1]), r[1]);
        stf(Ax, Ay, pf(L, iw[2]), r[2]); stf(Ax, Ay, pf(L, iw[3]), r[3]);
    }
    __syncthreads();                              // final reduce is cross-wave
    if (tid < 64) {
        int ya = tid >> 1, ff = tid & 1;
        float s = 0.0f;
        for (int rr = 0; rr < 4; ++rr)
            for (int yc = 0; yc < 4; ++yc) {
                float2 v = ldf(Ax, Ay, pf(rr * 2 + ff, yc * 32 + ya));
                s += v.x * v.x + v.y * v.y;
            }
        // remaining norm: (1/32)^2 for IFFT_Y32 inside |.|^2
        prob[((size_t)(b * 32 + xa) * 32 + ya) * 2 + ff] = s * (1.0f / 1024.0f);
    }
}

// ---------------------------------------------------------------------------
// K6: linear head, wave-shuffle reduction.
// ---------------------------------------------------------------------------
__global__ __launch_bounds__(256) void k6_linear(const float* __restrict__ prob,
                                                 const float* __restrict__ W,
                                                 const float* __restrict__ bv,
                                                 float* __restrict__ out) {
    __shared__ float red[40];
    int b = blockIdx.x;
    int tid = threadIdx.x;
    float acc[10];
#pragma unroll
    for (int c = 0; c < 10; ++c) acc[c] = 0.0f;
    for (int j = tid; j < 2048; j += 256) {
        float p = prob[(size_t)b * 2048 + j];
#pragma unroll
        for (int c = 0; c < 10; ++c) acc[c] += p * W[c * 2048 + j];
    }
    int wv = tid >> 6, ln = tid & 63;
#pragma unroll
    for (int c = 0; c < 10; ++c) {
        float s = acc[c];
        for (int off = 32; off > 0; off >>= 1) s += __shfl_down(s, off);
        if (ln == 0) red[wv * 10 + c] = s;
    }
    __syncthreads();
    if (tid < 10)
        out[b * 10 + tid] =
            red[tid] + red[10 + tid] + red[20 + tid] + red[30 + tid] + bv[tid];
}

// ---------------------------------------------------------------------------
extern "C" void kernel_launch(void* const* d_in, const int* in_sizes, int n_in,
                              void* d_out, int out_size, void* d_ws,
                              size_t ws_size, hipStream_t stream) {
    const float* images = (const float*)d_in[0];
    const float* mux0 = (const float*)d_in[1];
    const float* mux1 = (const float*)d_in[2];
    const float* mux2 = (const float*)d_in[3];
    const float* W = (const float*)d_in[4];
    const float* bv = (const float*)d_in[5];
    float* out = (float*)d_out;

    float2* ws0 = (float2*)d_ws;
    const size_t STATE_F2 = (size_t)512 * 128 * 128 * 2;  // 16,777,216
    float2* S = ws0;
    float2* U0 = ws0 + STATE_F2;
    float2* U1 = U0 + 65536;
    float2* U2 = U1 + 65536;
    float* prob = (float*)(U2 + 16384);
    const size_t needed =
        (STATE_F2 + 65536 + 65536 + 16384) * sizeof(float2) +
        (size_t)512 * 2048 * sizeof(float);
    if (ws_size < needed) return;

    k0_prep<<<144, 256, 0, stream>>>(mux0, mux1, mux2, U0, U1, U2);
    k1_encode<<<16384, 256, 0, stream>>>(images, S);
    k2_col0<<<16384, 256, 0, stream>>>(S, U0);
    k3_row1<<<16384, 256, 0, stream>>>(S, U1);
    k4_col2<<<16384, 256, 0, stream>>>(S, U2);
    k5_prob<<<16384, 256, 0, stream>>>(S, prob);
    k6_linear<<<512, 256, 0, stream>>>(prob, W, bv, out);
}